// Round 2
// baseline (195.976 us; speedup 1.0000x reference)
//
#include <hip/hip_runtime.h>
#include <hip/hip_bf16.h>

// Problem: B=16, S=2048, D=128 causal attention with pre-scale threshold.
//   A = Q@T^T;  A = (A>0.3 ? A : 0);  A += causal(-2^32);  A /= sqrt(128);
//   y = softmax(A) @ V
// Inputs/outputs are fp32 (per reference). Internal compute bf16 MFMA
// (test tolerance is bf16-grade: 2% relative).

#define S_LEN 2048
#define D_DIM 128
#define BQ 64
#define BK 64
#define THRESH 0.3f
#define SCALE 0.08838834764831845f   // 1/sqrt(128)

typedef __bf16 bf16x8 __attribute__((ext_vector_type(8)));
typedef float f32x4 __attribute__((ext_vector_type(4)));

__device__ inline bf16x8 cvt8(const float* p) {
    f32x4 a = *(const f32x4*)p;
    f32x4 b = *(const f32x4*)(p + 4);
    bf16x8 r;
    r[0] = (__bf16)a[0]; r[1] = (__bf16)a[1]; r[2] = (__bf16)a[2]; r[3] = (__bf16)a[3];
    r[4] = (__bf16)b[0]; r[5] = (__bf16)b[1]; r[6] = (__bf16)b[2]; r[7] = (__bf16)b[3];
    return r;
}

// -------- V transpose + downcast: V[b][s][d] fp32 -> Vt[b][d][s] bf16 --------
__global__ void vt_kernel(const float* __restrict__ V, __bf16* __restrict__ Vt) {
    __shared__ __bf16 tile[64][72];            // pad 72 to spread banks
    int bid = blockIdx.x;
    int b  = bid >> 6;                         // 64 tiles per batch
    int t2 = bid & 63;
    int s0 = (t2 >> 1) * 64;
    int d0 = (t2 & 1) * 64;
    int tid = threadIdx.x;                     // 256 threads
    #pragma unroll
    for (int it = 0; it < 2; ++it) {
        int row = it * 32 + (tid >> 3);
        int c   = (tid & 7) * 8;
        *(bf16x8*)(&tile[row][c]) =
            cvt8(V + ((size_t)b * S_LEN + s0 + row) * D_DIM + d0 + c);
    }
    __syncthreads();
    #pragma unroll
    for (int it = 0; it < 2; ++it) {
        int dr = it * 32 + (tid >> 3);
        int c  = (tid & 7) * 8;
        bf16x8 w;
        #pragma unroll
        for (int j = 0; j < 8; ++j) w[j] = tile[c + j][dr];
        *(bf16x8*)(Vt + ((size_t)b * D_DIM + d0 + dr) * S_LEN + s0 + c) = w;
    }
}

// ---------------- Flash attention, causal + threshold ----------------
// Block: 256 threads = 4 waves. One block per (batch, 64-query tile).
// Wave w owns q rows [q0+16w, q0+16w+15]. MFMA 16x16x32 bf16.
// A-frag: A[m=lane&15][k=quad*8+j]; C/D: col=lane&15, row=quad*4+r.
__global__ __launch_bounds__(256, 2)
void fa_kernel(const float* __restrict__ Q, const float* __restrict__ T,
               const __bf16* __restrict__ Vt, float* __restrict__ O) {
    __shared__ __bf16 Tt[64 * 136];        // key-major, stride 136 (2-way-free)
    __shared__ __bf16 Vl[128 * 72];        // d-major (V transposed), stride 72
    __shared__ __bf16 Pl[4][16 * 72];      // per-wave P scratch, stride 72

    int bid = blockIdx.x;
    int b   = bid & 15;
    int qt  = 31 - (bid >> 4);             // heavy tiles dispatch first
    int q0  = qt * BQ;

    int tid  = threadIdx.x;
    int lane = tid & 63;
    int wave = tid >> 6;
    int col  = lane & 15;
    int quad = lane >> 4;

    // Q fragments for this wave's 16 rows, full D=128, converted to bf16.
    const float* qptr = Q + ((size_t)b * S_LEN + (q0 + wave * 16 + col)) * D_DIM + quad * 8;
    bf16x8 qf[4];
    #pragma unroll
    for (int kk = 0; kk < 4; ++kk) qf[kk] = cvt8(qptr + kk * 32);

    f32x4 oacc[8];
    #pragma unroll
    for (int dt = 0; dt < 8; ++dt) oacc[dt] = {0.f, 0.f, 0.f, 0.f};
    float m_run[4], l_run[4];
    #pragma unroll
    for (int r = 0; r < 4; ++r) { m_run[r] = 0.0f; l_run[r] = 0.0f; }  // valid logits >= 0

    for (int kt = 0; kt <= qt; ++kt) {
        int k0 = kt * BK;
        __syncthreads();   // previous iteration's tile reads complete
        // Stage T tile (64 keys x 128 d, fp32->bf16) and V tile (bf16 from Vt).
        #pragma unroll
        for (int it = 0; it < 4; ++it) {
            int flat = it * 2048 + tid * 8;
            int row = flat >> 7;           // key 0..63
            int c   = flat & 127;          // d
            *(bf16x8*)(&Tt[row * 136 + c]) =
                cvt8(T + ((size_t)b * S_LEN + k0 + row) * D_DIM + c);
        }
        #pragma unroll
        for (int it = 0; it < 4; ++it) {
            int flat = it * 2048 + tid * 8;
            int d   = flat >> 6;           // 0..127
            int kk2 = flat & 63;
            bf16x8 v = *(const bf16x8*)(Vt + ((size_t)b * D_DIM + d) * S_LEN + k0 + kk2);
            *(bf16x8*)(&Vl[d * 72 + kk2]) = v;
        }
        __syncthreads();

        // ---- S = Q @ T^T for 16 q-rows x 64 keys (4 col-tiles of 16) ----
        f32x4 sacc[4];
        #pragma unroll
        for (int t = 0; t < 4; ++t) {
            sacc[t] = {0.f, 0.f, 0.f, 0.f};
            #pragma unroll
            for (int kk = 0; kk < 4; ++kk) {
                bf16x8 bf = *(const bf16x8*)(&Tt[(t * 16 + col) * 136 + kk * 32 + quad * 8]);
                sacc[t] = __builtin_amdgcn_mfma_f32_16x16x32_bf16(qf[kk], bf, sacc[t], 0, 0, 0);
            }
        }

        // ---- threshold, causal mask, scale ----
        bool diag = (kt == qt);
        float val[4][4];
        #pragma unroll
        for (int t = 0; t < 4; ++t)
            #pragma unroll
            for (int r = 0; r < 4; ++r) {
                float s = sacc[t][r];
                s = (s > THRESH) ? s : 0.0f;   // threshold on UNscaled score
                s *= SCALE;
                if (diag && (t * 16 + col > wave * 16 + quad * 4 + r)) s = -1e30f;
                val[t][r] = s;
            }

        // ---- online softmax update ----
        float pv[4][4];
        float alpha[4];
        #pragma unroll
        for (int r = 0; r < 4; ++r) {
            float mx = fmaxf(fmaxf(val[0][r], val[1][r]), fmaxf(val[2][r], val[3][r]));
            mx = fmaxf(mx, __shfl_xor(mx, 1));
            mx = fmaxf(mx, __shfl_xor(mx, 2));
            mx = fmaxf(mx, __shfl_xor(mx, 4));
            mx = fmaxf(mx, __shfl_xor(mx, 8));
            float mn = fmaxf(m_run[r], mx);
            alpha[r] = __expf(m_run[r] - mn);
            m_run[r] = mn;
            float s = 0.f;
            #pragma unroll
            for (int t = 0; t < 4; ++t) {
                float p = __expf(val[t][r] - mn);   // masked: exp(-1e30)=0
                pv[t][r] = p;
                s += p;
            }
            s += __shfl_xor(s, 1);
            s += __shfl_xor(s, 2);
            s += __shfl_xor(s, 4);
            s += __shfl_xor(s, 8);
            l_run[r] = l_run[r] * alpha[r] + s;
        }

        // rescale O accumulator
        #pragma unroll
        for (int dt = 0; dt < 8; ++dt)
            #pragma unroll
            for (int r = 0; r < 4; ++r) oacc[dt][r] *= alpha[r];

        // ---- P (C-layout) -> LDS -> A-layout for PV ----
        __bf16* pw = &Pl[wave][0];
        #pragma unroll
        for (int t = 0; t < 4; ++t)
            #pragma unroll
            for (int r = 0; r < 4; ++r)
                pw[(quad * 4 + r) * 72 + t * 16 + col] = (__bf16)pv[t][r];

        asm volatile("s_waitcnt lgkmcnt(0)" ::: "memory");  // wave-local RAW on Pl

        #pragma unroll
        for (int ks = 0; ks < 2; ++ks) {       // key chunks of 32
            bf16x8 af = *(const bf16x8*)(&pw[col * 72 + ks * 32 + quad * 8]);
            #pragma unroll
            for (int dt = 0; dt < 8; ++dt) {
                bf16x8 bf = *(const bf16x8*)(&Vl[(dt * 16 + col) * 72 + ks * 32 + quad * 8]);
                oacc[dt] = __builtin_amdgcn_mfma_f32_16x16x32_bf16(af, bf, oacc[dt], 0, 0, 0);
            }
        }
    }

    // ---- epilogue: O = acc / l, fp32 out ----
    float* optr = O + ((size_t)b * S_LEN + q0 + wave * 16) * D_DIM;
    #pragma unroll
    for (int dt = 0; dt < 8; ++dt) {
        #pragma unroll
        for (int r = 0; r < 4; ++r) {
            float o = oacc[dt][r] / l_run[r];  // l > 0 (diagonal key always valid)
            optr[(quad * 4 + r) * D_DIM + dt * 16 + col] = o;
        }
    }
}

extern "C" void kernel_launch(void* const* d_in, const int* in_sizes, int n_in,
                              void* d_out, int out_size, void* d_ws, size_t ws_size,
                              hipStream_t stream) {
    const float* Q = (const float*)d_in[0];
    const float* T = (const float*)d_in[1];
    const float* V = (const float*)d_in[2];
    __bf16* Vt = (__bf16*)d_ws;               // 16*128*2048*2 = 8 MB scratch
    float* O   = (float*)d_out;

    vt_kernel<<<16 * 64, 256, 0, stream>>>(V, Vt);
    fa_kernel<<<16 * 32, 256, 0, stream>>>(Q, T, Vt, O);
}

// Round 3
// 135.976 us; speedup vs baseline: 1.4412x; 1.4412x over previous
//
#include <hip/hip_runtime.h>
#include <hip/hip_bf16.h>

// B=16, S=2048, D=128 causal attention, pre-scale threshold:
//   A = Q@T^T; A = (A>0.3 ? A : 0); causal -2^32; /sqrt(128); softmax; @V
// fp32 in/out, bf16 MFMA internal.
// Key insight: post-threshold logits are in [0, ~9] -> fixed-max softmax
// (m=0) is numerically safe => no per-iteration cross-lane reductions.

#define S_LEN 2048
#define D_DIM 128
#define BQ 64
#define BK 64
#define THRESH 0.3f
#define SCALE 0.08838834764831845f   // 1/sqrt(128)

typedef __bf16 bf16x8 __attribute__((ext_vector_type(8)));
typedef float f32x4 __attribute__((ext_vector_type(4)));

// -------- V transpose + downcast: V[b][s][d] fp32 -> Vt[b][d][s] bf16 --------
// fp32 LDS tile, stride 65 dwords: both access phases are <=2-way (conflict-free).
__global__ void vt_kernel(const float* __restrict__ V, __bf16* __restrict__ Vt) {
    __shared__ float tile[64][65];
    int bid = blockIdx.x;
    int b  = bid >> 6;
    int t2 = bid & 63;
    int s0 = (t2 >> 1) * 64;
    int d0 = (t2 & 1) * 64;
    int tid = threadIdx.x;                     // 256 threads
    #pragma unroll
    for (int it = 0; it < 2; ++it) {
        int row = it * 32 + (tid >> 3);
        int c   = (tid & 7) * 8;
        const float* p = V + ((size_t)b * S_LEN + s0 + row) * D_DIM + d0 + c;
        *(f32x4*)(&tile[row][c])     = *(const f32x4*)p;
        *(f32x4*)(&tile[row][c + 4]) = *(const f32x4*)(p + 4);
    }
    __syncthreads();
    #pragma unroll
    for (int it = 0; it < 2; ++it) {
        int dr = it * 32 + (tid >> 3);
        int c  = (tid & 7) * 8;
        bf16x8 w;
        #pragma unroll
        for (int j = 0; j < 8; ++j) w[j] = (__bf16)tile[c + j][dr];
        *(bf16x8*)(Vt + ((size_t)b * D_DIM + d0 + dr) * S_LEN + s0 + c) = w;
    }
}

// ---------------- Flash attention, causal + threshold, fixed-max ----------------
// 256 threads = 4 waves; one block per (batch, 64-query tile); wave w owns
// q rows [q0+16w, q0+16w+15]. MFMA 16x16x32 bf16.
// A-frag: A[m=lane&15][k=quad*8+j]; C/D: col=lane&15, row=quad*4+r.
__global__ __launch_bounds__(256, 2)
void fa_kernel(const float* __restrict__ Q, const float* __restrict__ T,
               const __bf16* __restrict__ Vt, float* __restrict__ O) {
    __shared__ __bf16 Tt[64 * 136];        // key-major
    __shared__ __bf16 Vl[128 * 72];        // d-major (V transposed)
    __shared__ __bf16 Pl[4][16 * 72];      // per-wave P scratch

    int bid  = blockIdx.x;
    int b    = bid & 15;
    int half = bid >> 8;                   // 0: heavy half, 1: light half
    int idx  = (bid >> 4) & 15;
    int qt   = half == 0 ? (31 - idx) : idx;   // pair (i, i+256): 33 iters total
    int q0   = qt * BQ;

    int tid  = threadIdx.x;
    int lane = tid & 63;
    int wave = tid >> 6;
    int col  = lane & 15;
    int quad = lane >> 4;

    // Q fragments (16 rows x D=128) converted to bf16 once.
    const float* qptr = Q + ((size_t)b * S_LEN + (q0 + wave * 16 + col)) * D_DIM + quad * 8;
    bf16x8 qf[4];
    #pragma unroll
    for (int kk = 0; kk < 4; ++kk) {
        f32x4 a = *(const f32x4*)(qptr + kk * 32);
        f32x4 c = *(const f32x4*)(qptr + kk * 32 + 4);
        #pragma unroll
        for (int j = 0; j < 4; ++j) { qf[kk][j] = (__bf16)a[j]; qf[kk][4 + j] = (__bf16)c[j]; }
    }

    f32x4 oacc[8];
    #pragma unroll
    for (int dt = 0; dt < 8; ++dt) oacc[dt] = {0.f, 0.f, 0.f, 0.f};
    float lsum[4] = {0.f, 0.f, 0.f, 0.f};

    // ---- staging helpers (register prefetch -> LDS) ----
    f32x4 tr[8]; bf16x8 vr[4];
    auto loadTiles = [&](int k0) {
        #pragma unroll
        for (int it = 0; it < 4; ++it) {
            int flat = it * 2048 + tid * 8;
            int row = flat >> 7, c = flat & 127;
            const float* p = T + ((size_t)b * S_LEN + k0 + row) * D_DIM + c;
            tr[2 * it]     = *(const f32x4*)p;
            tr[2 * it + 1] = *(const f32x4*)(p + 4);
        }
        #pragma unroll
        for (int it = 0; it < 4; ++it) {
            int flat = it * 2048 + tid * 8;
            int d = flat >> 6, kk2 = flat & 63;
            vr[it] = *(const bf16x8*)(Vt + ((size_t)b * D_DIM + d) * S_LEN + k0 + kk2);
        }
    };
    auto storeTiles = [&]() {
        #pragma unroll
        for (int it = 0; it < 4; ++it) {
            int flat = it * 2048 + tid * 8;
            int row = flat >> 7, c = flat & 127;
            bf16x8 w;
            #pragma unroll
            for (int j = 0; j < 4; ++j) {
                w[j]     = (__bf16)tr[2 * it][j];
                w[4 + j] = (__bf16)tr[2 * it + 1][j];
            }
            *(bf16x8*)(&Tt[row * 136 + c]) = w;
        }
        #pragma unroll
        for (int it = 0; it < 4; ++it) {
            int flat = it * 2048 + tid * 8;
            int d = flat >> 6, kk2 = flat & 63;
            *(bf16x8*)(&Vl[d * 72 + kk2]) = vr[it];
        }
    };

    loadTiles(0);
    storeTiles();
    __syncthreads();

    for (int kt = 0; kt <= qt; ++kt) {
        if (kt < qt) loadTiles((kt + 1) * BK);   // prefetch next tile into regs

        // ---- S = Q @ T^T (16 q-rows x 64 keys) ----
        f32x4 sacc[4];
        #pragma unroll
        for (int t = 0; t < 4; ++t) {
            sacc[t] = {0.f, 0.f, 0.f, 0.f};
            #pragma unroll
            for (int kk = 0; kk < 4; ++kk) {
                bf16x8 bf = *(const bf16x8*)(&Tt[(t * 16 + col) * 136 + kk * 32 + quad * 8]);
                sacc[t] = __builtin_amdgcn_mfma_f32_16x16x32_bf16(qf[kk], bf, sacc[t], 0, 0, 0);
            }
        }

        // ---- fixed-max softmax weights: p = masked?0 : (s>thr? exp(s*sc) : 1) ----
        bool diag = (kt == qt);
        float p[4][4];
        #pragma unroll
        for (int t = 0; t < 4; ++t)
            #pragma unroll
            for (int r = 0; r < 4; ++r) {
                float s = sacc[t][r];
                float e = __expf(s * SCALE);
                float w = (s > THRESH) ? e : 1.0f;
                if (diag && (t * 16 + col > wave * 16 + quad * 4 + r)) w = 0.0f;
                p[t][r] = w;
            }
        #pragma unroll
        for (int r = 0; r < 4; ++r)
            lsum[r] += (p[0][r] + p[1][r]) + (p[2][r] + p[3][r]);

        // ---- P (C-layout) -> LDS -> A-layout ----
        __bf16* pw = &Pl[wave][0];
        #pragma unroll
        for (int t = 0; t < 4; ++t)
            #pragma unroll
            for (int r = 0; r < 4; ++r)
                pw[(quad * 4 + r) * 72 + t * 16 + col] = (__bf16)p[t][r];

        asm volatile("s_waitcnt lgkmcnt(0)" ::: "memory");  // wave-local RAW on Pl

        #pragma unroll
        for (int ks = 0; ks < 2; ++ks) {
            bf16x8 af = *(const bf16x8*)(&pw[col * 72 + ks * 32 + quad * 8]);
            #pragma unroll
            for (int dt = 0; dt < 8; ++dt) {
                bf16x8 bf = *(const bf16x8*)(&Vl[(dt * 16 + col) * 72 + ks * 32 + quad * 8]);
                oacc[dt] = __builtin_amdgcn_mfma_f32_16x16x32_bf16(af, bf, oacc[dt], 0, 0, 0);
            }
        }

        __syncthreads();                    // all waves done reading this tile
        if (kt < qt) storeTiles();          // regs -> LDS (waits vmcnt here)
        __syncthreads();                    // next tile visible
    }

    // ---- final l reduction across the 16 col-lanes, then store ----
    #pragma unroll
    for (int r = 0; r < 4; ++r) {
        float l = lsum[r];
        l += __shfl_xor(l, 1);
        l += __shfl_xor(l, 2);
        l += __shfl_xor(l, 4);
        l += __shfl_xor(l, 8);
        lsum[r] = 1.0f / l;                // diagonal key always contributes >=1
    }
    float* optr = O + ((size_t)b * S_LEN + q0 + wave * 16) * D_DIM;
    #pragma unroll
    for (int dt = 0; dt < 8; ++dt)
        #pragma unroll
        for (int r = 0; r < 4; ++r)
            optr[(quad * 4 + r) * D_DIM + dt * 16 + col] = oacc[dt][r] * lsum[r];
}

extern "C" void kernel_launch(void* const* d_in, const int* in_sizes, int n_in,
                              void* d_out, int out_size, void* d_ws, size_t ws_size,
                              hipStream_t stream) {
    const float* Q = (const float*)d_in[0];
    const float* T = (const float*)d_in[1];
    const float* V = (const float*)d_in[2];
    __bf16* Vt = (__bf16*)d_ws;               // 16*128*2048*2 = 8 MB scratch
    float* O   = (float*)d_out;

    vt_kernel<<<16 * 64, 256, 0, stream>>>(V, Vt);
    fa_kernel<<<16 * 32, 256, 0, stream>>>(Q, T, Vt, O);
}